// Round 7
// baseline (458.601 us; speedup 1.0000x reference)
//
#include <hip/hip_runtime.h>
#include <hip/hip_bf16.h>
#include <cmath>

// Problem constants
#define HIDDEN 2048
#define SEQ 2048
#define BATCH 2
#define NQ 16
#define NKV 8
#define HD 128
#define RANKL 8
#define LORA_SCALE 2.0f
#define INV_SQRT_D 0.08838834764831845f
#define LOG2E 1.4426950408889634f
#define SM_SCALE (INV_SQRT_D * LOG2E)

typedef unsigned short ushort_t;
typedef __bf16 bf16x8 __attribute__((ext_vector_type(8)));
typedef _Float16 f16x4 __attribute__((ext_vector_type(4)));
typedef float f32x4 __attribute__((ext_vector_type(4)));

static __device__ __forceinline__ ushort_t f2bf(float f) {
    __hip_bfloat16 h = __float2bfloat16(f);
    return *(ushort_t*)&h;
}
static __device__ __forceinline__ float bf2f(ushort_t u) {
    unsigned int v = ((unsigned int)u) << 16;
    return __builtin_bit_cast(float, v);
}
static __device__ __forceinline__ void gload_lds16(const ushort_t* g, ushort_t* l) {
    __builtin_amdgcn_global_load_lds(
        (const __attribute__((address_space(1))) unsigned int*)g,
        (__attribute__((address_space(3))) unsigned int*)l, 16, 0, 0);
}

// ---------------------------------------------------------------------------
// Prep: x cast + q/k/v LoRA-A (blocks 0..4095), weight casts (4096..10239),
// rope table TRANSPOSED tabT[p][s] (blocks 10240..10751)
// ---------------------------------------------------------------------------
__global__ __launch_bounds__(256) void prep_kernel(
    const float* __restrict__ X, ushort_t* __restrict__ Xbf,
    const float* __restrict__ qA, const float* __restrict__ kA,
    const float* __restrict__ vA,
    float* __restrict__ oq, float* __restrict__ ok, float* __restrict__ ov,
    const float* __restrict__ Wq, const float* __restrict__ Wk,
    const float* __restrict__ Wv, const float* __restrict__ Wo,
    ushort_t* __restrict__ Wqb, ushort_t* __restrict__ Wkb,
    ushort_t* __restrict__ Wvb, ushort_t* __restrict__ Wob,
    float2* __restrict__ rope_tab)
{
    __shared__ float wred[4][3][RANKL];
    const int blk = blockIdx.x;
    const int t = threadIdx.x;

    if (blk >= 10240) {                      // rope table tabT[p][s]
        int idx = (blk - 10240) * 256 + t;   // 0..131071 = p*2048 + s
        int p = idx >> 11, s = idx & 2047;
        float inv = exp2f(-(float)p * 0.20762050593046f);
        float ang = (float)s * inv;
        rope_tab[idx] = make_float2(cosf(ang), sinf(ang));
        return;
    }
    if (blk >= 4096) {                       // weight casts
        size_t i = (size_t)(blk - 4096) * 256 + t;
        const float* src; ushort_t* dst; size_t j;
        if (i < 524288)       { src = Wq; dst = Wqb; j = i; }
        else if (i < 786432)  { src = Wk; dst = Wkb; j = i - 524288; }
        else if (i < 1048576) { src = Wv; dst = Wvb; j = i - 786432; }
        else                  { src = Wo; dst = Wob; j = i - 1048576; }
        const float4* p = (const float4*)src + j * 2;
        float4 a = p[0], b = p[1];
        uint4 o;
        o.x = (unsigned int)f2bf(a.x) | ((unsigned int)f2bf(a.y) << 16);
        o.y = (unsigned int)f2bf(a.z) | ((unsigned int)f2bf(a.w) << 16);
        o.z = (unsigned int)f2bf(b.x) | ((unsigned int)f2bf(b.y) << 16);
        o.w = (unsigned int)f2bf(b.z) | ((unsigned int)f2bf(b.w) << 16);
        *(uint4*)(dst + j * 8) = o;
        return;
    }

    // x cast + LoRA-A for q,k,v
    int m = blk;
    int c0 = t * 8;
    const float* xr = X + (size_t)m * HIDDEN + c0;
    float4 a = *(const float4*)xr;
    float4 b = *(const float4*)(xr + 4);
    float xv[8] = {a.x, a.y, a.z, a.w, b.x, b.y, b.z, b.w};
    uint4 o;
    o.x = (unsigned int)f2bf(xv[0]) | ((unsigned int)f2bf(xv[1]) << 16);
    o.y = (unsigned int)f2bf(xv[2]) | ((unsigned int)f2bf(xv[3]) << 16);
    o.z = (unsigned int)f2bf(xv[4]) | ((unsigned int)f2bf(xv[5]) << 16);
    o.w = (unsigned int)f2bf(xv[6]) | ((unsigned int)f2bf(xv[7]) << 16);
    *(uint4*)(Xbf + (size_t)m * HIDDEN + c0) = o;

    float p[3][RANKL];
#pragma unroll
    for (int w = 0; w < 3; w++)
#pragma unroll
        for (int r = 0; r < RANKL; r++) p[w][r] = 0.f;
    const float* Aw[3] = {qA, kA, vA};
#pragma unroll
    for (int e = 0; e < 8; e++) {
        float x8 = xv[e];
#pragma unroll
        for (int w = 0; w < 3; w++)
#pragma unroll
            for (int r = 0; r < RANKL; r++)
                p[w][r] += x8 * Aw[w][r * HIDDEN + c0 + e];
    }
#pragma unroll
    for (int w = 0; w < 3; w++)
#pragma unroll
        for (int r = 0; r < RANKL; r++) {
            float v = p[w][r];
            v += __shfl_xor(v, 32); v += __shfl_xor(v, 16);
            v += __shfl_xor(v, 8);  v += __shfl_xor(v, 4);
            v += __shfl_xor(v, 2);  v += __shfl_xor(v, 1);
            p[w][r] = v;
        }
    int wave = t >> 6, lane = t & 63;
    if (lane == 0) {
#pragma unroll
        for (int w = 0; w < 3; w++)
#pragma unroll
            for (int r = 0; r < RANKL; r++) wred[wave][w][r] = p[w][r];
    }
    __syncthreads();
    if (t < 3 * RANKL) {
        int w = t / RANKL, r = t % RANKL;
        float s = wred[0][w][r] + wred[1][w][r] + wred[2][w][r] + wred[3][w][r];
        float* dst = (w == 0) ? oq : (w == 1) ? ok : ov;
        dst[(size_t)m * RANKL + r] = s;
    }
}

// bf16-input LoRA A-projection (for o)
__global__ __launch_bounds__(256) void lora_xa_bf16(
    const ushort_t* __restrict__ X, const float* __restrict__ Aw,
    float* __restrict__ out, int K)
{
    int m = blockIdx.x;
    int t = threadIdx.x;
    const ushort_t* xr = X + (size_t)m * K;
    float p[RANKL];
#pragma unroll
    for (int r = 0; r < RANKL; r++) p[r] = 0.f;
    for (int c = t; c < K; c += 256) {
        float xv = bf2f(xr[c]);
#pragma unroll
        for (int r = 0; r < RANKL; r++) p[r] += xv * Aw[r * K + c];
    }
#pragma unroll
    for (int r = 0; r < RANKL; r++) {
        float v = p[r];
        v += __shfl_xor(v, 32); v += __shfl_xor(v, 16);
        v += __shfl_xor(v, 8);  v += __shfl_xor(v, 4);
        v += __shfl_xor(v, 2);  v += __shfl_xor(v, 1);
        p[r] = v;
    }
    __shared__ float wred[4][RANKL];
    int wave = t >> 6, lane = t & 63;
    if (lane == 0) {
#pragma unroll
        for (int r = 0; r < RANKL; r++) wred[wave][r] = p[r];
    }
    __syncthreads();
    if (t < RANKL) {
        out[(size_t)m * RANKL + t] =
            wred[0][t] + wred[1][t] + wred[2][t] + wred[3][t];
    }
}

// ---------------------------------------------------------------------------
// QKV GEMM. Epilogue: Q plain (rope moved to attention), K rope, V f16
// transposed. grid (32, 32): bc<16 Q, <24 K, else V.
// ---------------------------------------------------------------------------
__global__ __launch_bounds__(256) void gemm_qkv(
    const ushort_t* __restrict__ A,
    const ushort_t* __restrict__ Wqb, const ushort_t* __restrict__ Wkb,
    const ushort_t* __restrict__ Wvb,
    ushort_t* __restrict__ qb, ushort_t* __restrict__ kb,
    ushort_t* __restrict__ vtb,
    const float* __restrict__ xa_q, const float* __restrict__ xa_k,
    const float* __restrict__ xa_v,
    const float* __restrict__ qB, const float* __restrict__ kB,
    const float* __restrict__ vB,
    const float2* __restrict__ rope_tab)
{
    __shared__ ushort_t As[128 * 32];
    __shared__ ushort_t Bs[128 * 32];

    const int t = threadIdx.x;
    const int lane = t & 63;
    const int w = t >> 6;
    const int quad = lane >> 4;
    const int c = lane & 15;
    const int q4 = quad * 4;

    const int bm = blockIdx.x * 128;
    const int bc = blockIdx.y;
    int mode, bn;                    // 0=Q(plain), 1=K(rope), 2=V(f16 transpose)
    const ushort_t* B; const float* xa; const float* LB;
    if (bc < 16)      { mode = 0; B = Wqb; xa = xa_q; LB = qB; bn = bc * 128; }
    else if (bc < 24) { mode = 1; B = Wkb; xa = xa_k; LB = kB; bn = (bc - 16) * 128; }
    else              { mode = 2; B = Wvb; xa = xa_v; LB = vB; bn = (bc - 24) * 128; }

    const int wm = (w & 1) * 64;
    const int wn = (w >> 1) * 64;
    const int K = HIDDEN;

    f32x4 acc[4][4];
#pragma unroll
    for (int i = 0; i < 4; i++)
#pragma unroll
        for (int j = 0; j < 4; j++) acc[i][j] = (f32x4){0.f, 0.f, 0.f, 0.f};

    const int p0 = w * 64 + lane;
    const int p1 = 256 + w * 64 + lane;
    const int r0 = p0 >> 2, g0 = (p0 & 3) ^ ((p0 >> 3) & 3);
    const int r1 = p1 >> 2, g1 = (p1 & 3) ^ ((p1 >> 3) & 3);
    const ushort_t* gA0 = A + (size_t)(bm + r0) * K + g0 * 8;
    const ushort_t* gA1 = A + (size_t)(bm + r1) * K + g1 * 8;
    const ushort_t* gB0 = B + (size_t)(bn + r0) * K + g0 * 8;
    const ushort_t* gB1 = B + (size_t)(bn + r1) * K + g1 * 8;
    ushort_t* lA0 = As + (size_t)(w * 64) * 8;
    ushort_t* lA1 = As + (size_t)(256 + w * 64) * 8;
    ushort_t* lB0 = Bs + (size_t)(w * 64) * 8;
    ushort_t* lB1 = Bs + (size_t)(256 + w * 64) * 8;

    const int csw = quad ^ ((c >> 1) & 3);

    for (int k0 = 0; k0 < K; k0 += 32) {
        __syncthreads();
        gload_lds16(gA0 + k0, lA0);
        gload_lds16(gA1 + k0, lA1);
        gload_lds16(gB0 + k0, lB0);
        gload_lds16(gB1 + k0, lB1);
        __syncthreads();

        bf16x8 af[4], bfr[4];
#pragma unroll
        for (int mt = 0; mt < 4; mt++)
            af[mt] = *(const bf16x8*)&As[((wm + mt * 16 + c) * 4 + csw) * 8];
#pragma unroll
        for (int nt = 0; nt < 4; nt++)
            bfr[nt] = *(const bf16x8*)&Bs[((wn + nt * 16 + c) * 4 + csw) * 8];
#pragma unroll
        for (int mt = 0; mt < 4; mt++)
#pragma unroll
            for (int nt = 0; nt < 4; nt++)
                acc[mt][nt] = __builtin_amdgcn_mfma_f32_16x16x32_bf16(
                    af[mt], bfr[nt], acc[mt][nt], 0, 0, 0);
    }

    // ---- epilogue
    const int b = bm >> 11;
    float lb[4][RANKL];
#pragma unroll
    for (int nt = 0; nt < 4; nt++) {
        int col = bn + wn + nt * 16 + c;
        float4 u = *(const float4*)&LB[(size_t)col * RANKL];
        float4 v = *(const float4*)&LB[(size_t)col * RANKL + 4];
        lb[nt][0] = u.x; lb[nt][1] = u.y; lb[nt][2] = u.z; lb[nt][3] = u.w;
        lb[nt][4] = v.x; lb[nt][5] = v.y; lb[nt][6] = v.z; lb[nt][7] = v.w;
    }
    const float ssign = (c & 1) ? 1.f : -1.f;

#pragma unroll
    for (int mt = 0; mt < 4; mt++) {
        float la[4][RANKL];
#pragma unroll
        for (int r = 0; r < 4; r++) {
            int row = bm + wm + mt * 16 + q4 + r;
            float4 u = *(const float4*)&xa[(size_t)row * RANKL];
            float4 v = *(const float4*)&xa[(size_t)row * RANKL + 4];
            la[r][0] = u.x; la[r][1] = u.y; la[r][2] = u.z; la[r][3] = u.w;
            la[r][4] = v.x; la[r][5] = v.y; la[r][6] = v.z; la[r][7] = v.w;
        }
        const int s0 = (bm + wm + mt * 16 + q4) & (SEQ - 1);
#pragma unroll
        for (int nt = 0; nt < 4; nt++) {
            const int col = bn + wn + nt * 16 + c;
            const int d = col & (HD - 1);
            float vals[4];
#pragma unroll
            for (int r = 0; r < 4; r++) {
                float s = 0.f;
#pragma unroll
                for (int k = 0; k < RANKL; k++) s += la[r][k] * lb[nt][k];
                vals[r] = acc[mt][nt][r] + LORA_SCALE * s;
            }
            if (mode == 2) {
                // V: packed f16 transposed store (4 consecutive s)
                const int kvh = col >> 7;
                ushort_t pack[4];
#pragma unroll
                for (int r = 0; r < 4; r++)
                    pack[r] = __builtin_bit_cast(ushort_t, (_Float16)vals[r]);
                *(uint2*)&vtb[((size_t)(b * NKV + kvh) * HD + d) * SEQ + s0]
                    = *(uint2*)pack;
            } else if (mode == 1) {
                // K: rope via lane-pair shuffle + tabT[p][s]
                const int pq = d >> 1;
#pragma unroll
                for (int r = 0; r < 4; r++) {
                    float pv = __shfl_xor(vals[r], 1);
                    float2 cs = rope_tab[(size_t)pq * SEQ + s0 + r];
                    float outv = vals[r] * cs.x + pv * ssign * cs.y;
                    const int kvh = col >> 7;
                    kb[((size_t)(b * NKV + kvh) * SEQ + s0 + r) * HD + d]
                        = f2bf(outv);
                }
            } else {
                // Q: plain store (rope applied in attention)
                const int hh = col >> 7;
#pragma unroll
                for (int r = 0; r < 4; r++)
                    qb[((size_t)(b * NQ + hh) * SEQ + s0 + r) * HD + d]
                        = f2bf(vals[r]);
            }
        }
    }
}

// ---------------------------------------------------------------------------
// Output projection (fp32 out) with fused o-LoRA
// ---------------------------------------------------------------------------
__global__ __launch_bounds__(256) void gemm_wo(
    const ushort_t* __restrict__ A, const ushort_t* __restrict__ Wob,
    float* __restrict__ out, const float* __restrict__ xa_o,
    const float* __restrict__ oB)
{
    __shared__ ushort_t As[128 * 32];
    __shared__ ushort_t Bs[128 * 32];

    const int t = threadIdx.x;
    const int lane = t & 63;
    const int w = t >> 6;
    const int quad = lane >> 4;
    const int c = lane & 15;

    const int bm = blockIdx.x * 128;
    const int bn = blockIdx.y * 128;
    const int wm = (w & 1) * 64;
    const int wn = (w >> 1) * 64;
    const int K = NQ * HD;
    const int N = HIDDEN;

    f32x4 acc[4][4];
#pragma unroll
    for (int i = 0; i < 4; i++)
#pragma unroll
        for (int j = 0; j < 4; j++) acc[i][j] = (f32x4){0.f, 0.f, 0.f, 0.f};

    const int p0 = w * 64 + lane;
    const int p1 = 256 + w * 64 + lane;
    const int r0 = p0 >> 2, g0 = (p0 & 3) ^ ((p0 >> 3) & 3);
    const int r1 = p1 >> 2, g1 = (p1 & 3) ^ ((p1 >> 3) & 3);
    const ushort_t* gA0 = A + (size_t)(bm + r0) * K + g0 * 8;
    const ushort_t* gA1 = A + (size_t)(bm + r1) * K + g1 * 8;
    const ushort_t* gB0 = Wob + (size_t)(bn + r0) * K + g0 * 8;
    const ushort_t* gB1 = Wob + (size_t)(bn + r1) * K + g1 * 8;
    ushort_t* lA0 = As + (size_t)(w * 64) * 8;
    ushort_t* lA1 = As + (size_t)(256 + w * 64) * 8;
    ushort_t* lB0 = Bs + (size_t)(w * 64) * 8;
    ushort_t* lB1 = Bs + (size_t)(256 + w * 64) * 8;

    const int csw = quad ^ ((c >> 1) & 3);

    for (int k0 = 0; k0 < K; k0 += 32) {
        __syncthreads();
        gload_lds16(gA0 + k0, lA0);
        gload_lds16(gA1 + k0, lA1);
        gload_lds16(gB0 + k0, lB0);
        gload_lds16(gB1 + k0, lB1);
        __syncthreads();

        bf16x8 af[4], bfr[4];
#pragma unroll
        for (int mt = 0; mt < 4; mt++)
            af[mt] = *(const bf16x8*)&As[((wm + mt * 16 + c) * 4 + csw) * 8];
#pragma unroll
        for (int nt = 0; nt < 4; nt++)
            bfr[nt] = *(const bf16x8*)&Bs[((wn + nt * 16 + c) * 4 + csw) * 8];
#pragma unroll
        for (int mt = 0; mt < 4; mt++)
#pragma unroll
            for (int nt = 0; nt < 4; nt++)
                acc[mt][nt] = __builtin_amdgcn_mfma_f32_16x16x32_bf16(
                    af[mt], bfr[nt], acc[mt][nt], 0, 0, 0);
    }

    float lb[4][RANKL];
#pragma unroll
    for (int nt = 0; nt < 4; nt++) {
        int col = bn + wn + nt * 16 + c;
        float4 u = *(const float4*)&oB[(size_t)col * RANKL];
        float4 v = *(const float4*)&oB[(size_t)col * RANKL + 4];
        lb[nt][0] = u.x; lb[nt][1] = u.y; lb[nt][2] = u.z; lb[nt][3] = u.w;
        lb[nt][4] = v.x; lb[nt][5] = v.y; lb[nt][6] = v.z; lb[nt][7] = v.w;
    }
#pragma unroll
    for (int mt = 0; mt < 4; mt++) {
        float la[4][RANKL];
#pragma unroll
        for (int r = 0; r < 4; r++) {
            int row = bm + wm + mt * 16 + quad * 4 + r;
            float4 u = *(const float4*)&xa_o[(size_t)row * RANKL];
            float4 v = *(const float4*)&xa_o[(size_t)row * RANKL + 4];
            la[r][0] = u.x; la[r][1] = u.y; la[r][2] = u.z; la[r][3] = u.w;
            la[r][4] = v.x; la[r][5] = v.y; la[r][6] = v.z; la[r][7] = v.w;
        }
#pragma unroll
        for (int nt = 0; nt < 4; nt++) {
#pragma unroll
            for (int r = 0; r < 4; r++) {
                float s = 0.f;
#pragma unroll
                for (int k = 0; k < RANKL; k++) s += la[r][k] * lb[nt][k];
                size_t row = bm + wm + mt * 16 + quad * 4 + r;
                size_t col = bn + wn + nt * 16 + c;
                out[row * N + col] = acc[mt][nt][r] + LORA_SCALE * s;
            }
        }
    }
}

// ---------------------------------------------------------------------------
// MFMA flash attention v5.
// S^T formulation: sT = MFMA(K, Q) -> per-lane q-column = c. P stays in
// registers (f16, B-operand layout) -> PV via mfma_f32_16x16x16f16 with
// V^T (f16) as A-operand. No P LDS round-trip. Q-rope applied in-kernel.
// Wave covers 32 q-rows (q-tiles a and 31-a) in ONE key-loop: for tiles <= a
// both q-sets reuse the staged K/V tile (halves LDS-read amplification).
// Block = 4 waves x 16 rows per set; grid 512; a flipped in 2nd half so
// co-resident blocks stage complementary tile counts.
// Q,K bf16 [b][h/kvh][s][128]; V f16 [b][kvh][d][s]; O bf16 [b*s][h*128+d].
// ---------------------------------------------------------------------------
__global__ __launch_bounds__(256, 3) void attn_mfma5(
    const ushort_t* __restrict__ Q, const ushort_t* __restrict__ K,
    const ushort_t* __restrict__ V, ushort_t* __restrict__ O,
    const float2* __restrict__ tabT)
{
    __shared__ ushort_t Ks[64 * 128];       // 16 KB bf16
    __shared__ ushort_t Vs[128 * 64];       // 16 KB f16 [d][keys]

    const int t = threadIdx.x;
    const int lane = t & 63;
    const int w = t >> 6;
    const int quad = lane >> 4;
    const int c = lane & 15;
    const int c7 = c & 7;

    const int half = blockIdx.x >> 8;
    const int rem = blockIdx.x & 255;
    const int head = half * 16 + (rem >> 4);     // b*NQ + h
    const int aa = rem & 15;
    const int a = half ? (15 - aa) : aa;
    const int h = head & (NQ - 1);
    const int b = head >> 4;
    const int kvh = b * NKV + (h >> 1);

    const ushort_t* Kg = K + (size_t)kvh * SEQ * HD;
    const ushort_t* Vg = V + (size_t)kvh * HD * SEQ;

    const ushort_t* gK[4]; const ushort_t* gV[4];
    int lo4[4];
#pragma unroll
    for (int i = 0; i < 4; i++) {
        int cid = t + 256 * i;
        int kr = cid >> 4, kc = cid & 15;
        gK[i] = Kg + (size_t)kr * HD + ((kc ^ (kr & 7)) * 8);
        int vd = cid >> 3, vc = cid & 7;
        gV[i] = Vg + (size_t)vd * SEQ + ((vc ^ (vd & 7)) * 8);
        lo4[i] = (i * 256 + (t & ~63)) * 8;
    }

    // Q rows for the two sets
    const int slo = a * 64 + w * 16 + c;          // low q-tile row (global s)
    const int shi = (31 - a) * 64 + w * 16 + c;   // high q-tile row

    // ---- load Q fragments + rope in registers
    const ushort_t* Qlo = Q + ((size_t)head * SEQ + slo) * HD;
    const ushort_t* Qhi = Q + ((size_t)head * SEQ + shi) * HD;
    bf16x8 qlo[4], qhi[4];
#pragma unroll
    for (int ch = 0; ch < 4; ch++) {
        const int pbase = ch * 16 + quad * 4;
        uint4 rl = *(const uint4*)(Qlo + ch * 32 + quad * 8);
        uint4 rh = *(const uint4*)(Qhi + ch * 32 + quad * 8);
        unsigned* pl = (unsigned*)&rl;
        unsigned* ph = (unsigned*)&rh;
#pragma unroll
        for (int i = 0; i < 4; i++) {
            float2 cl = tabT[(size_t)(pbase + i) * SEQ + slo];
            float2 chs = tabT[(size_t)(pbase + i) * SEQ + shi];
            float xr = bf2f((ushort_t)(pl[i] & 0xffff));
            float xi = bf2f((ushort_t)(pl[i] >> 16));
            pl[i] = (unsigned)f2bf(xr * cl.x - xi * cl.y)
                  | ((unsigned)f2bf(xr * cl.y + xi * cl.x) << 16);
            xr = bf2f((ushort_t)(ph[i] & 0xffff));
            xi = bf2f((ushort_t)(ph[i] >> 16));
            ph[i] = (unsigned)f2bf(xr * chs.x - xi * chs.y)
                  | ((unsigned)f2bf(xr * chs.y + xi * chs.x) << 16);
        }
        qlo[ch] = __builtin_bit_cast(bf16x8, rl);
        qhi[ch] = __builtin_bit_cast(bf16x8, rh);
    }

    f32x4 o_lo[8], o_hi[8];
#pragma unroll
    for (int i = 0; i < 8; i++) {
        o_lo[i] = (f32x4){0.f, 0.f, 0.f, 0.f};
        o_hi[i] = (f32x4){0.f, 0.f, 0.f, 0.f};
    }
    float lp_lo = 0.f, lp_hi = 0.f;

    const int ntiles = 32 - a;

    for (int tile = 0; tile < ntiles; ++tile) {
        const int j0 = tile * 64;
        __syncthreads();
#pragma unroll
        for (int i = 0; i < 4; i++)
            gload_lds16(gK[i] + (size_t)j0 * HD, &Ks[lo4[i]]);
#pragma unroll
        for (int i = 0; i < 4; i++)
            gload_lds16(gV[i] + j0, &Vs[lo4[i]]);
        __syncthreads();

        const bool lo_act = (tile <= a);

        // ---- QK^T (transposed): sT rows = keys, cols = q
        f32x4 sl[4], sh[4];
#pragma unroll
        for (int tt = 0; tt < 4; tt++) {
            sl[tt] = (f32x4){0.f, 0.f, 0.f, 0.f};
            sh[tt] = (f32x4){0.f, 0.f, 0.f, 0.f};
        }
#pragma unroll
        for (int tt = 0; tt < 4; tt++) {
            const int krow = tt * 16 + c;
#pragma unroll
            for (int ch = 0; ch < 4; ch++) {
                bf16x8 kf = *(const bf16x8*)
                    &Ks[krow * 128 + (((ch * 4 + quad) ^ c7) * 8)];
                sh[tt] = __builtin_amdgcn_mfma_f32_16x16x32_bf16(
                    kf, qhi[ch], sh[tt], 0, 0, 0);
                if (lo_act)
                    sl[tt] = __builtin_amdgcn_mfma_f32_16x16x32_bf16(
                        kf, qlo[ch], sl[tt], 0, 0, 0);
            }
        }

        // ---- softmax (constant-max) + pack P^T to f16 registers
        f16x4 pl_[4], ph_[4];
        const bool dhi = (tile == ntiles - 1);
        const bool dlo = (tile == a);
#pragma unroll
        for (int tt = 0; tt < 4; tt++) {
#pragma unroll
            for (int r = 0; r < 4; r++) {
                const int key = j0 + tt * 16 + quad * 4 + r;
                float pv = exp2f(sh[tt][r] * SM_SCALE);
                if (dhi && key > shi) pv = 0.f;
                lp_hi += pv;
                ph_[tt][r] = (_Float16)pv;
                if (lo_act) {
                    float pw = exp2f(sl[tt][r] * SM_SCALE);
                    if (dlo && key > slo) pw = 0.f;
                    lp_lo += pw;
                    pl_[tt][r] = (_Float16)pw;
                }
            }
        }

        // ---- PV: o^T[d][q] += V^T * P^T  (K=16 f16 MFMA)
#pragma unroll
        for (int dt = 0; dt < 8; dt++) {
            const int vrow = dt * 16 + c;
#pragma unroll
            for (int tt = 0; tt < 4; tt++) {
                const int cch = tt * 2 + (quad >> 1);
                f16x4 vf = *(const f16x4*)
                    &Vs[vrow * 64 + ((cch ^ c7) * 8) + (quad & 1) * 4];
                o_hi[dt] = __builtin_amdgcn_mfma_f32_16x16x16f16(
                    vf, ph_[tt], o_hi[dt], 0, 0, 0);
                if (lo_act)
                    o_lo[dt] = __builtin_amdgcn_mfma_f32_16x16x16f16(
                        vf, pl_[tt], o_lo[dt], 0, 0, 0);
            }
        }
    }

    // ---- epilogue: reduce l across quads (keys split over quads), store
    lp_hi += __shfl_xor(lp_hi, 16);
    lp_hi += __shfl_xor(lp_hi, 32);
    lp_lo += __shfl_xor(lp_lo, 16);
    lp_lo += __shfl_xor(lp_lo, 32);
    const float ih = 1.f / lp_hi, il = 1.f / lp_lo;

    const size_t colbase = h * HD + quad * 4;
    size_t rhi = ((size_t)b * SEQ + shi) * (NQ * HD) + colbase;
    size_t rlo = ((size_t)b * SEQ + slo) * (NQ * HD) + colbase;
#pragma unroll
    for (int dt = 0; dt < 8; dt++) {
        ushort_t ph2[4], pl2[4];
#pragma unroll
        for (int r = 0; r < 4; r++) {
            ph2[r] = f2bf(o_hi[dt][r] * ih);
            pl2[r] = f2bf(o_lo[dt][r] * il);
        }
        *(uint2*)&O[rhi + dt * 16] = *(uint2*)ph2;
        *(uint2*)&O[rlo + dt * 16] = *(uint2*)pl2;
    }
}

// ---------------------------------------------------------------------------
// Launch
// ---------------------------------------------------------------------------
extern "C" void kernel_launch(void* const* d_in, const int* in_sizes, int n_in,
                              void* d_out, int out_size, void* d_ws, size_t ws_size,
                              hipStream_t stream)
{
    const float* x  = (const float*)d_in[0];
    const float* Wq = (const float*)d_in[1];
    const float* Wk = (const float*)d_in[2];
    const float* Wv = (const float*)d_in[3];
    const float* Wo = (const float*)d_in[4];
    const float* qA = (const float*)d_in[5];
    const float* qB = (const float*)d_in[6];
    const float* kA = (const float*)d_in[7];
    const float* kB = (const float*)d_in[8];
    const float* vA = (const float*)d_in[9];
    const float* vB = (const float*)d_in[10];
    const float* oA = (const float*)d_in[11];
    const float* oB = (const float*)d_in[12];
    float* out = (float*)d_out;
    float* ws = (float*)d_ws;

    const int M = BATCH * SEQ;           // 4096

    float* xa_q = ws;
    float* xa_k = ws + 32768;
    float* xa_v = ws + 65536;
    float* xa_o = ws + 98304;
    float2* rope_tab = (float2*)(ws + 131072);      // tabT[p][s], 64x2048
    ushort_t* qb  = (ushort_t*)(ws + 393216);       // bf16 [B][16][S][128]
    ushort_t* kb  = (ushort_t*)(ws + 4587520);      // bf16 [B][8][S][128] roped
    ushort_t* vtb = (ushort_t*)(ws + 6684672);      // f16  [B][8][128][S]
    ushort_t* attn_out = (ushort_t*)(ws + 8781824); // bf16 [4096][2048]
    ushort_t* xbf = (ushort_t*)(ws + 12976128);     // bf16 4096x2048
    ushort_t* Wqb = (ushort_t*)(ws + 17170432);
    ushort_t* Wkb = (ushort_t*)(ws + 19267584);
    ushort_t* Wvb = (ushort_t*)(ws + 20316160);
    ushort_t* Wob = (ushort_t*)(ws + 21364736);

    // prep: x cast + LoRA-A(q,k,v) + weight casts + rope table (transposed)
    prep_kernel<<<10752, 256, 0, stream>>>(
        x, xbf, qA, kA, vA, xa_q, xa_k, xa_v,
        Wq, Wk, Wv, Wo, Wqb, Wkb, Wvb, Wob, rope_tab);

    // QKV projection: LoRA fused; K roped, V f16-transposed, Q plain
    gemm_qkv<<<dim3(M / 128, 32), 256, 0, stream>>>(
        xbf, Wqb, Wkb, Wvb, qb, kb, vtb,
        xa_q, xa_k, xa_v, qB, kB, vB, rope_tab);

    // flash attention (Q-rope in-kernel, dual q-tile K/V reuse)
    attn_mfma5<<<512, 256, 0, stream>>>(qb, kb, vtb, attn_out, rope_tab);

    // output projection with fused o-LoRA
    lora_xa_bf16<<<M, 256, 0, stream>>>(attn_out, oA, xa_o, NQ * HD);
    gemm_wo<<<dim3(M / 128, HIDDEN / 128), 256, 0, stream>>>(
        attn_out, Wob, out, xa_o, oB);
}

// Round 8
// 453.581 us; speedup vs baseline: 1.0111x; 1.0111x over previous
//
#include <hip/hip_runtime.h>
#include <hip/hip_bf16.h>
#include <cmath>

// Problem constants
#define HIDDEN 2048
#define SEQ 2048
#define BATCH 2
#define NQ 16
#define NKV 8
#define HD 128
#define RANKL 8
#define LORA_SCALE 2.0f
#define INV_SQRT_D 0.08838834764831845f
#define LOG2E 1.4426950408889634f
#define SM_SCALE (INV_SQRT_D * LOG2E)

typedef unsigned short ushort_t;
typedef __bf16 bf16x8 __attribute__((ext_vector_type(8)));
typedef float f32x4 __attribute__((ext_vector_type(4)));

static __device__ __forceinline__ ushort_t f2bf(float f) {
    __hip_bfloat16 h = __float2bfloat16(f);
    return *(ushort_t*)&h;
}
static __device__ __forceinline__ float bf2f(ushort_t u) {
    unsigned int v = ((unsigned int)u) << 16;
    return __builtin_bit_cast(float, v);
}
static __device__ __forceinline__ void gload_lds16(const ushort_t* g, ushort_t* l) {
    __builtin_amdgcn_global_load_lds(
        (const __attribute__((address_space(1))) unsigned int*)g,
        (__attribute__((address_space(3))) unsigned int*)l, 16, 0, 0);
}

// ---------------------------------------------------------------------------
// Prep: x cast + q/k/v LoRA-A (blocks 0..4095), weight casts (4096..10239),
// rope table TRANSPOSED tabT[p][s] (blocks 10240..10751)
// ---------------------------------------------------------------------------
__global__ __launch_bounds__(256) void prep_kernel(
    const float* __restrict__ X, ushort_t* __restrict__ Xbf,
    const float* __restrict__ qA, const float* __restrict__ kA,
    const float* __restrict__ vA,
    float* __restrict__ oq, float* __restrict__ ok, float* __restrict__ ov,
    const float* __restrict__ Wq, const float* __restrict__ Wk,
    const float* __restrict__ Wv, const float* __restrict__ Wo,
    ushort_t* __restrict__ Wqb, ushort_t* __restrict__ Wkb,
    ushort_t* __restrict__ Wvb, ushort_t* __restrict__ Wob,
    float2* __restrict__ rope_tab)
{
    __shared__ float wred[4][3][RANKL];
    const int blk = blockIdx.x;
    const int t = threadIdx.x;

    if (blk >= 10240) {                      // rope table tabT[p][s]
        int idx = (blk - 10240) * 256 + t;   // p*2048 + s
        int p = idx >> 11, s = idx & 2047;
        float inv = exp2f(-(float)p * 0.20762050593046f);
        float ang = (float)s * inv;
        rope_tab[idx] = make_float2(cosf(ang), sinf(ang));
        return;
    }
    if (blk >= 4096) {                       // weight casts
        size_t i = (size_t)(blk - 4096) * 256 + t;
        const float* src; ushort_t* dst; size_t j;
        if (i < 524288)       { src = Wq; dst = Wqb; j = i; }
        else if (i < 786432)  { src = Wk; dst = Wkb; j = i - 524288; }
        else if (i < 1048576) { src = Wv; dst = Wvb; j = i - 786432; }
        else                  { src = Wo; dst = Wob; j = i - 1048576; }
        const float4* p = (const float4*)src + j * 2;
        float4 a = p[0], b = p[1];
        uint4 o;
        o.x = (unsigned int)f2bf(a.x) | ((unsigned int)f2bf(a.y) << 16);
        o.y = (unsigned int)f2bf(a.z) | ((unsigned int)f2bf(a.w) << 16);
        o.z = (unsigned int)f2bf(b.x) | ((unsigned int)f2bf(b.y) << 16);
        o.w = (unsigned int)f2bf(b.z) | ((unsigned int)f2bf(b.w) << 16);
        *(uint4*)(dst + j * 8) = o;
        return;
    }

    // x cast + LoRA-A for q,k,v
    int m = blk;
    int c0 = t * 8;
    const float* xr = X + (size_t)m * HIDDEN + c0;
    float4 a = *(const float4*)xr;
    float4 b = *(const float4*)(xr + 4);
    float xv[8] = {a.x, a.y, a.z, a.w, b.x, b.y, b.z, b.w};
    uint4 o;
    o.x = (unsigned int)f2bf(xv[0]) | ((unsigned int)f2bf(xv[1]) << 16);
    o.y = (unsigned int)f2bf(xv[2]) | ((unsigned int)f2bf(xv[3]) << 16);
    o.z = (unsigned int)f2bf(xv[4]) | ((unsigned int)f2bf(xv[5]) << 16);
    o.w = (unsigned int)f2bf(xv[6]) | ((unsigned int)f2bf(xv[7]) << 16);
    *(uint4*)(Xbf + (size_t)m * HIDDEN + c0) = o;

    float p[3][RANKL];
#pragma unroll
    for (int w = 0; w < 3; w++)
#pragma unroll
        for (int r = 0; r < RANKL; r++) p[w][r] = 0.f;
    const float* Aw[3] = {qA, kA, vA};
#pragma unroll
    for (int e = 0; e < 8; e++) {
        float x8 = xv[e];
#pragma unroll
        for (int w = 0; w < 3; w++)
#pragma unroll
            for (int r = 0; r < RANKL; r++)
                p[w][r] += x8 * Aw[w][r * HIDDEN + c0 + e];
    }
#pragma unroll
    for (int w = 0; w < 3; w++)
#pragma unroll
        for (int r = 0; r < RANKL; r++) {
            float v = p[w][r];
            v += __shfl_xor(v, 32); v += __shfl_xor(v, 16);
            v += __shfl_xor(v, 8);  v += __shfl_xor(v, 4);
            v += __shfl_xor(v, 2);  v += __shfl_xor(v, 1);
            p[w][r] = v;
        }
    int wave = t >> 6, lane = t & 63;
    if (lane == 0) {
#pragma unroll
        for (int w = 0; w < 3; w++)
#pragma unroll
            for (int r = 0; r < RANKL; r++) wred[wave][w][r] = p[w][r];
    }
    __syncthreads();
    if (t < 3 * RANKL) {
        int w = t / RANKL, r = t % RANKL;
        float s = wred[0][w][r] + wred[1][w][r] + wred[2][w][r] + wred[3][w][r];
        float* dst = (w == 0) ? oq : (w == 1) ? ok : ov;
        dst[(size_t)m * RANKL + r] = s;
    }
}

// bf16-input LoRA A-projection (for o)
__global__ __launch_bounds__(256) void lora_xa_bf16(
    const ushort_t* __restrict__ X, const float* __restrict__ Aw,
    float* __restrict__ out, int K)
{
    int m = blockIdx.x;
    int t = threadIdx.x;
    const ushort_t* xr = X + (size_t)m * K;
    float p[RANKL];
#pragma unroll
    for (int r = 0; r < RANKL; r++) p[r] = 0.f;
    for (int c = t; c < K; c += 256) {
        float xv = bf2f(xr[c]);
#pragma unroll
        for (int r = 0; r < RANKL; r++) p[r] += xv * Aw[r * K + c];
    }
#pragma unroll
    for (int r = 0; r < RANKL; r++) {
        float v = p[r];
        v += __shfl_xor(v, 32); v += __shfl_xor(v, 16);
        v += __shfl_xor(v, 8);  v += __shfl_xor(v, 4);
        v += __shfl_xor(v, 2);  v += __shfl_xor(v, 1);
        p[r] = v;
    }
    __shared__ float wred[4][RANKL];
    int wave = t >> 6, lane = t & 63;
    if (lane == 0) {
#pragma unroll
        for (int r = 0; r < RANKL; r++) wred[wave][r] = p[r];
    }
    __syncthreads();
    if (t < RANKL) {
        out[(size_t)m * RANKL + t] =
            wred[0][t] + wred[1][t] + wred[2][t] + wred[3][t];
    }
}

// ---------------------------------------------------------------------------
// QKV GEMM. Epilogue: Q plain (rope in attention), K rope, V bf16 transposed.
// grid (32, 32): bc<16 Q, <24 K, else V.
// ---------------------------------------------------------------------------
__global__ __launch_bounds__(256) void gemm_qkv(
    const ushort_t* __restrict__ A,
    const ushort_t* __restrict__ Wqb, const ushort_t* __restrict__ Wkb,
    const ushort_t* __restrict__ Wvb,
    ushort_t* __restrict__ qb, ushort_t* __restrict__ kb,
    ushort_t* __restrict__ vtb,
    const float* __restrict__ xa_q, const float* __restrict__ xa_k,
    const float* __restrict__ xa_v,
    const float* __restrict__ qB, const float* __restrict__ kB,
    const float* __restrict__ vB,
    const float2* __restrict__ rope_tab)
{
    __shared__ ushort_t As[128 * 32];
    __shared__ ushort_t Bs[128 * 32];

    const int t = threadIdx.x;
    const int lane = t & 63;
    const int w = t >> 6;
    const int quad = lane >> 4;
    const int c = lane & 15;
    const int q4 = quad * 4;

    const int bm = blockIdx.x * 128;
    const int bc = blockIdx.y;
    int mode, bn;                    // 0=Q(plain), 1=K(rope), 2=V(bf16 transpose)
    const ushort_t* B; const float* xa; const float* LB;
    if (bc < 16)      { mode = 0; B = Wqb; xa = xa_q; LB = qB; bn = bc * 128; }
    else if (bc < 24) { mode = 1; B = Wkb; xa = xa_k; LB = kB; bn = (bc - 16) * 128; }
    else              { mode = 2; B = Wvb; xa = xa_v; LB = vB; bn = (bc - 24) * 128; }

    const int wm = (w & 1) * 64;
    const int wn = (w >> 1) * 64;
    const int K = HIDDEN;

    f32x4 acc[4][4];
#pragma unroll
    for (int i = 0; i < 4; i++)
#pragma unroll
        for (int j = 0; j < 4; j++) acc[i][j] = (f32x4){0.f, 0.f, 0.f, 0.f};

    const int p0 = w * 64 + lane;
    const int p1 = 256 + w * 64 + lane;
    const int r0 = p0 >> 2, g0 = (p0 & 3) ^ ((p0 >> 3) & 3);
    const int r1 = p1 >> 2, g1 = (p1 & 3) ^ ((p1 >> 3) & 3);
    const ushort_t* gA0 = A + (size_t)(bm + r0) * K + g0 * 8;
    const ushort_t* gA1 = A + (size_t)(bm + r1) * K + g1 * 8;
    const ushort_t* gB0 = B + (size_t)(bn + r0) * K + g0 * 8;
    const ushort_t* gB1 = B + (size_t)(bn + r1) * K + g1 * 8;
    ushort_t* lA0 = As + (size_t)(w * 64) * 8;
    ushort_t* lA1 = As + (size_t)(256 + w * 64) * 8;
    ushort_t* lB0 = Bs + (size_t)(w * 64) * 8;
    ushort_t* lB1 = Bs + (size_t)(256 + w * 64) * 8;

    const int csw = quad ^ ((c >> 1) & 3);

    for (int k0 = 0; k0 < K; k0 += 32) {
        __syncthreads();
        gload_lds16(gA0 + k0, lA0);
        gload_lds16(gA1 + k0, lA1);
        gload_lds16(gB0 + k0, lB0);
        gload_lds16(gB1 + k0, lB1);
        __syncthreads();

        bf16x8 af[4], bfr[4];
#pragma unroll
        for (int mt = 0; mt < 4; mt++)
            af[mt] = *(const bf16x8*)&As[((wm + mt * 16 + c) * 4 + csw) * 8];
#pragma unroll
        for (int nt = 0; nt < 4; nt++)
            bfr[nt] = *(const bf16x8*)&Bs[((wn + nt * 16 + c) * 4 + csw) * 8];
#pragma unroll
        for (int mt = 0; mt < 4; mt++)
#pragma unroll
            for (int nt = 0; nt < 4; nt++)
                acc[mt][nt] = __builtin_amdgcn_mfma_f32_16x16x32_bf16(
                    af[mt], bfr[nt], acc[mt][nt], 0, 0, 0);
    }

    // ---- epilogue
    const int b = bm >> 11;
    float lb[4][RANKL];
#pragma unroll
    for (int nt = 0; nt < 4; nt++) {
        int col = bn + wn + nt * 16 + c;
        float4 u = *(const float4*)&LB[(size_t)col * RANKL];
        float4 v = *(const float4*)&LB[(size_t)col * RANKL + 4];
        lb[nt][0] = u.x; lb[nt][1] = u.y; lb[nt][2] = u.z; lb[nt][3] = u.w;
        lb[nt][4] = v.x; lb[nt][5] = v.y; lb[nt][6] = v.z; lb[nt][7] = v.w;
    }
    const float ssign = (c & 1) ? 1.f : -1.f;

#pragma unroll
    for (int mt = 0; mt < 4; mt++) {
        float la[4][RANKL];
#pragma unroll
        for (int r = 0; r < 4; r++) {
            int row = bm + wm + mt * 16 + q4 + r;
            float4 u = *(const float4*)&xa[(size_t)row * RANKL];
            float4 v = *(const float4*)&xa[(size_t)row * RANKL + 4];
            la[r][0] = u.x; la[r][1] = u.y; la[r][2] = u.z; la[r][3] = u.w;
            la[r][4] = v.x; la[r][5] = v.y; la[r][6] = v.z; la[r][7] = v.w;
        }
        const int s0 = (bm + wm + mt * 16 + q4) & (SEQ - 1);
#pragma unroll
        for (int nt = 0; nt < 4; nt++) {
            const int col = bn + wn + nt * 16 + c;
            const int d = col & (HD - 1);
            float vals[4];
#pragma unroll
            for (int r = 0; r < 4; r++) {
                float s = 0.f;
#pragma unroll
                for (int k = 0; k < RANKL; k++) s += la[r][k] * lb[nt][k];
                vals[r] = acc[mt][nt][r] + LORA_SCALE * s;
            }
            if (mode == 2) {
                // V: packed bf16 transposed store (4 consecutive s)
                const int kvh = col >> 7;
                ushort_t pack[4];
#pragma unroll
                for (int r = 0; r < 4; r++) pack[r] = f2bf(vals[r]);
                *(uint2*)&vtb[((size_t)(b * NKV + kvh) * HD + d) * SEQ + s0]
                    = *(uint2*)pack;
            } else if (mode == 1) {
                // K: rope via lane-pair shuffle + tabT[p][s]
                const int pq = d >> 1;
#pragma unroll
                for (int r = 0; r < 4; r++) {
                    float pv = __shfl_xor(vals[r], 1);
                    float2 cs = rope_tab[(size_t)pq * SEQ + s0 + r];
                    float outv = vals[r] * cs.x + pv * ssign * cs.y;
                    const int kvh = col >> 7;
                    kb[((size_t)(b * NKV + kvh) * SEQ + s0 + r) * HD + d]
                        = f2bf(outv);
                }
            } else {
                // Q: plain store (rope applied in attention)
                const int hh = col >> 7;
#pragma unroll
                for (int r = 0; r < 4; r++)
                    qb[((size_t)(b * NQ + hh) * SEQ + s0 + r) * HD + d]
                        = f2bf(vals[r]);
            }
        }
    }
}

// ---------------------------------------------------------------------------
// Output projection (fp32 out) with fused o-LoRA
// ---------------------------------------------------------------------------
__global__ __launch_bounds__(256) void gemm_wo(
    const ushort_t* __restrict__ A, const ushort_t* __restrict__ Wob,
    float* __restrict__ out, const float* __restrict__ xa_o,
    const float* __restrict__ oB)
{
    __shared__ ushort_t As[128 * 32];
    __shared__ ushort_t Bs[128 * 32];

    const int t = threadIdx.x;
    const int lane = t & 63;
    const int w = t >> 6;
    const int quad = lane >> 4;
    const int c = lane & 15;

    const int bm = blockIdx.x * 128;
    const int bn = blockIdx.y * 128;
    const int wm = (w & 1) * 64;
    const int wn = (w >> 1) * 64;
    const int K = NQ * HD;
    const int N = HIDDEN;

    f32x4 acc[4][4];
#pragma unroll
    for (int i = 0; i < 4; i++)
#pragma unroll
        for (int j = 0; j < 4; j++) acc[i][j] = (f32x4){0.f, 0.f, 0.f, 0.f};

    const int p0 = w * 64 + lane;
    const int p1 = 256 + w * 64 + lane;
    const int r0 = p0 >> 2, g0 = (p0 & 3) ^ ((p0 >> 3) & 3);
    const int r1 = p1 >> 2, g1 = (p1 & 3) ^ ((p1 >> 3) & 3);
    const ushort_t* gA0 = A + (size_t)(bm + r0) * K + g0 * 8;
    const ushort_t* gA1 = A + (size_t)(bm + r1) * K + g1 * 8;
    const ushort_t* gB0 = Wob + (size_t)(bn + r0) * K + g0 * 8;
    const ushort_t* gB1 = Wob + (size_t)(bn + r1) * K + g1 * 8;
    ushort_t* lA0 = As + (size_t)(w * 64) * 8;
    ushort_t* lA1 = As + (size_t)(256 + w * 64) * 8;
    ushort_t* lB0 = Bs + (size_t)(w * 64) * 8;
    ushort_t* lB1 = Bs + (size_t)(256 + w * 64) * 8;

    const int csw = quad ^ ((c >> 1) & 3);

    for (int k0 = 0; k0 < K; k0 += 32) {
        __syncthreads();
        gload_lds16(gA0 + k0, lA0);
        gload_lds16(gA1 + k0, lA1);
        gload_lds16(gB0 + k0, lB0);
        gload_lds16(gB1 + k0, lB1);
        __syncthreads();

        bf16x8 af[4], bfr[4];
#pragma unroll
        for (int mt = 0; mt < 4; mt++)
            af[mt] = *(const bf16x8*)&As[((wm + mt * 16 + c) * 4 + csw) * 8];
#pragma unroll
        for (int nt = 0; nt < 4; nt++)
            bfr[nt] = *(const bf16x8*)&Bs[((wn + nt * 16 + c) * 4 + csw) * 8];
#pragma unroll
        for (int mt = 0; mt < 4; mt++)
#pragma unroll
            for (int nt = 0; nt < 4; nt++)
                acc[mt][nt] = __builtin_amdgcn_mfma_f32_16x16x32_bf16(
                    af[mt], bfr[nt], acc[mt][nt], 0, 0, 0);
    }

    float lb[4][RANKL];
#pragma unroll
    for (int nt = 0; nt < 4; nt++) {
        int col = bn + wn + nt * 16 + c;
        float4 u = *(const float4*)&oB[(size_t)col * RANKL];
        float4 v = *(const float4*)&oB[(size_t)col * RANKL + 4];
        lb[nt][0] = u.x; lb[nt][1] = u.y; lb[nt][2] = u.z; lb[nt][3] = u.w;
        lb[nt][4] = v.x; lb[nt][5] = v.y; lb[nt][6] = v.z; lb[nt][7] = v.w;
    }
#pragma unroll
    for (int mt = 0; mt < 4; mt++) {
        float la[4][RANKL];
#pragma unroll
        for (int r = 0; r < 4; r++) {
            int row = bm + wm + mt * 16 + quad * 4 + r;
            float4 u = *(const float4*)&xa_o[(size_t)row * RANKL];
            float4 v = *(const float4*)&xa_o[(size_t)row * RANKL + 4];
            la[r][0] = u.x; la[r][1] = u.y; la[r][2] = u.z; la[r][3] = u.w;
            la[r][4] = v.x; la[r][5] = v.y; la[r][6] = v.z; la[r][7] = v.w;
        }
#pragma unroll
        for (int nt = 0; nt < 4; nt++) {
#pragma unroll
            for (int r = 0; r < 4; r++) {
                float s = 0.f;
#pragma unroll
                for (int k = 0; k < RANKL; k++) s += la[r][k] * lb[nt][k];
                size_t row = bm + wm + mt * 16 + quad * 4 + r;
                size_t col = bn + wn + nt * 16 + c;
                out[row * N + col] = acc[mt][nt][r] + LORA_SCALE * s;
            }
        }
    }
}

// ---------------------------------------------------------------------------
// MFMA flash attention v6.
// Block = 128 threads = 2 waves; wave owns 32 q-rows (2 m-tiles of 16).
// Each kf/vf ds_read_b128 feeds 2 MFMAs -> ~2x less LDS traffic per work unit
// (the measured bottleneck). q-tiles {a, 31-a} (64 rows) sequential ->
// uniform 33 key-tiles/block; 512 blocks = exactly 2/CU (LDS 72.5 KB).
// Ping-pong K/V staging, one barrier per tile. Q-rope in-kernel.
// Constant-max softmax. Q,K bf16 [b][h/kvh][s][128]; V bf16 [b][kvh][d][s];
// O bf16 [b*s][h*128+d].
// ---------------------------------------------------------------------------
__global__ __launch_bounds__(128) void attn_mfma6(
    const ushort_t* __restrict__ Q, const ushort_t* __restrict__ K,
    const ushort_t* __restrict__ V, ushort_t* __restrict__ O,
    const float2* __restrict__ tabT)
{
    __shared__ ushort_t Ks[2][64 * 128];    // 16 KB x2
    __shared__ ushort_t Vs[2][128 * 64];    // 16 KB x2
    __shared__ ushort_t Psh[2][2][16 * 68]; // 8.5 KB  [wave][mt]

    const int t = threadIdx.x;          // 0..127
    const int lane = t & 63;
    const int w = t >> 6;               // 0..1
    const int quad = lane >> 4;
    const int c = lane & 15;
    const int q4 = quad * 4;
    const int c7 = c & 7;

    const int head = blockIdx.x >> 4;   // b*NQ + h
    const int a = blockIdx.x & 15;
    const int h = head & (NQ - 1);
    const int b = head >> 4;
    const int kvh = b * NKV + (h >> 1);

    const ushort_t* Kg = K + (size_t)kvh * SEQ * HD;
    const ushort_t* Vg = V + (size_t)kvh * HD * SEQ;

    // staging: 1024 16B-chunks each for K and V; 8 gload instr per tile each.
    // chunk id cid = i*128 + w*64 + lane; LDS offset = cid*16B.
    const ushort_t* gK[8]; const ushort_t* gV[8];
    int lo8[8];
#pragma unroll
    for (int i = 0; i < 8; i++) {
        int cid = i * 128 + w * 64 + lane;
        int kr = cid >> 4, kc = cid & 15;
        gK[i] = Kg + (size_t)kr * HD + ((kc ^ (kr & 7)) * 8);
        int vd = cid >> 3, vc = cid & 7;
        gV[i] = Vg + (size_t)vd * SEQ + ((vc ^ (vd & 7)) * 8);
        lo8[i] = (i * 128 + w * 64) * 8;
    }

#pragma unroll 1
    for (int half = 0; half < 2; half++) {
        const int qt = half ? (31 - a) : a;
        const int qb0 = qt * 64;

        // ---- Q fragments + rope in registers (2 m-tiles)
        bf16x8 qf[2][4];
#pragma unroll
        for (int mt = 0; mt < 2; mt++) {
            const int srow = qb0 + w * 32 + mt * 16 + c;
            const ushort_t* Qg = Q + ((size_t)head * SEQ + srow) * HD;
#pragma unroll
            for (int ch = 0; ch < 4; ch++) {
                const int pbase = ch * 16 + quad * 4;
                uint4 rl = *(const uint4*)(Qg + ch * 32 + quad * 8);
                unsigned* pl = (unsigned*)&rl;
#pragma unroll
                for (int i = 0; i < 4; i++) {
                    float2 cs = tabT[(size_t)(pbase + i) * SEQ + srow];
                    float xr = bf2f((ushort_t)(pl[i] & 0xffff));
                    float xi = bf2f((ushort_t)(pl[i] >> 16));
                    pl[i] = (unsigned)f2bf(xr * cs.x - xi * cs.y)
                          | ((unsigned)f2bf(xr * cs.y + xi * cs.x) << 16);
                }
                qf[mt][ch] = __builtin_bit_cast(bf16x8, rl);
            }
        }

        f32x4 o[2][8];
#pragma unroll
        for (int mt = 0; mt < 2; mt++)
#pragma unroll
            for (int i = 0; i < 8; i++) o[mt][i] = (f32x4){0.f, 0.f, 0.f, 0.f};
        float lp[2][4] = {{0.f, 0.f, 0.f, 0.f}, {0.f, 0.f, 0.f, 0.f}};

        const int ntiles = qt + 1;

        // prime tile 0 -> buffer 0
        __syncthreads();
#pragma unroll
        for (int i = 0; i < 8; i++) gload_lds16(gK[i], &Ks[0][lo8[i]]);
#pragma unroll
        for (int i = 0; i < 8; i++) gload_lds16(gV[i], &Vs[0][lo8[i]]);
        __syncthreads();

        for (int tile = 0; tile < ntiles; ++tile) {
            const int cur = tile & 1;
            if (tile + 1 < ntiles) {
                const int j1 = (tile + 1) * 64;
#pragma unroll
                for (int i = 0; i < 8; i++)
                    gload_lds16(gK[i] + (size_t)j1 * HD, &Ks[cur ^ 1][lo8[i]]);
#pragma unroll
                for (int i = 0; i < 8; i++)
                    gload_lds16(gV[i] + j1, &Vs[cur ^ 1][lo8[i]]);
            }

            // ---- QK^T: each kf feeds both m-tiles
            f32x4 s[2][4];
#pragma unroll
            for (int tt = 0; tt < 4; tt++) {
                s[0][tt] = (f32x4){0.f, 0.f, 0.f, 0.f};
                s[1][tt] = (f32x4){0.f, 0.f, 0.f, 0.f};
            }
#pragma unroll
            for (int tt = 0; tt < 4; tt++) {
                const int krow = tt * 16 + c;
#pragma unroll
                for (int ch = 0; ch < 4; ch++) {
                    bf16x8 kf = *(const bf16x8*)
                        &Ks[cur][krow * 128 + (((ch * 4 + quad) ^ c7) * 8)];
                    s[0][tt] = __builtin_amdgcn_mfma_f32_16x16x32_bf16(
                        qf[0][ch], kf, s[0][tt], 0, 0, 0);
                    s[1][tt] = __builtin_amdgcn_mfma_f32_16x16x32_bf16(
                        qf[1][ch], kf, s[1][tt], 0, 0, 0);
                }
            }

            // ---- constant-max softmax, P to per-wave LDS
            const bool diag = (tile == qt);
            const int j0 = tile * 64;
#pragma unroll
            for (int mt = 0; mt < 2; mt++) {
                ushort_t* Pw = Psh[w][mt];
                const int rowbase = qb0 + w * 32 + mt * 16;
#pragma unroll
                for (int r = 0; r < 4; r++) {
                    const int row_g = rowbase + q4 + r;
#pragma unroll
                    for (int tt = 0; tt < 4; tt++) {
                        float p = exp2f(s[mt][tt][r] * SM_SCALE);
                        if (diag && (j0 + tt * 16 + c > row_g)) p = 0.f;
                        Pw[(q4 + r) * 68 + tt * 16 + c] = f2bf(p);
                        lp[mt][r] += p;
                    }
                }
            }

            // ---- P fragments (A-layout)
            bf16x8 pf[2][2];
#pragma unroll
            for (int mt = 0; mt < 2; mt++)
#pragma unroll
                for (int ch = 0; ch < 2; ch++) {
                    int base = c * 68 + ch * 32 + quad * 8;
                    uint2 aa = *(const uint2*)&Psh[w][mt][base];
                    uint2 bb = *(const uint2*)&Psh[w][mt][base + 4];
                    uint4 u; u.x = aa.x; u.y = aa.y; u.z = bb.x; u.w = bb.y;
                    pf[mt][ch] = __builtin_bit_cast(bf16x8, u);
                }

            // ---- PV: each vf feeds both m-tiles
#pragma unroll
            for (int dt = 0; dt < 8; dt++) {
                const int vrow = dt * 16 + c;
#pragma unroll
                for (int ch = 0; ch < 2; ch++) {
                    bf16x8 vf = *(const bf16x8*)
                        &Vs[cur][vrow * 64 + (((ch * 4 + quad) ^ c7) * 8)];
                    o[0][dt] = __builtin_amdgcn_mfma_f32_16x16x32_bf16(
                        pf[0][ch], vf, o[0][dt], 0, 0, 0);
                    o[1][dt] = __builtin_amdgcn_mfma_f32_16x16x32_bf16(
                        pf[1][ch], vf, o[1][dt], 0, 0, 0);
                }
            }
            __syncthreads();   // prefetch drained + everyone done with cur
        }

        // ---- epilogue
#pragma unroll
        for (int mt = 0; mt < 2; mt++) {
            float inv[4];
#pragma unroll
            for (int r = 0; r < 4; r++) {
                float v = lp[mt][r];
                v += __shfl_xor(v, 1);
                v += __shfl_xor(v, 2);
                v += __shfl_xor(v, 4);
                v += __shfl_xor(v, 8);
                inv[r] = 1.f / v;
            }
            size_t base = ((size_t)b * SEQ + qb0 + w * 32 + mt * 16 + q4)
                          * (NQ * HD) + h * HD + c;
#pragma unroll
            for (int r = 0; r < 4; r++)
#pragma unroll
                for (int dt = 0; dt < 8; dt++)
                    O[base + (size_t)r * (NQ * HD) + dt * 16] =
                        f2bf(o[mt][dt][r] * inv[r]);
        }
    }
}

// ---------------------------------------------------------------------------
// Launch
// ---------------------------------------------------------------------------
extern "C" void kernel_launch(void* const* d_in, const int* in_sizes, int n_in,
                              void* d_out, int out_size, void* d_ws, size_t ws_size,
                              hipStream_t stream)
{
    const float* x  = (const float*)d_in[0];
    const float* Wq = (const float*)d_in[1];
    const float* Wk = (const float*)d_in[2];
    const float* Wv = (const float*)d_in[3];
    const float* Wo = (const float*)d_in[4];
    const float* qA = (const float*)d_in[5];
    const float* qB = (const float*)d_in[6];
    const float* kA = (const float*)d_in[7];
    const float* kB = (const float*)d_in[8];
    const float* vA = (const float*)d_in[9];
    const float* vB = (const float*)d_in[10];
    const float* oA = (const float*)d_in[11];
    const float* oB = (const float*)d_in[12];
    float* out = (float*)d_out;
    float* ws = (float*)d_ws;

    const int M = BATCH * SEQ;           // 4096

    float* xa_q = ws;
    float* xa_k = ws + 32768;
    float* xa_v = ws + 65536;
    float* xa_o = ws + 98304;
    float2* rope_tab = (float2*)(ws + 131072);      // tabT[p][s], 64x2048
    ushort_t* qb  = (ushort_t*)(ws + 393216);       // bf16 [B][16][S][128]
    ushort_t* kb  = (ushort_t*)(ws + 4587520);      // bf16 [B][8][S][128] roped
    ushort_t* vtb = (ushort_t*)(ws + 6684672);      // bf16 [B][8][128][S]
    ushort_t* attn_out = (ushort_t*)(ws + 8781824); // bf16 [4096][2048]
    ushort_t* xbf = (ushort_t*)(ws + 12976128);     // bf16 4096x2048
    ushort_t* Wqb = (ushort_t*)(ws + 17170432);
    ushort_t* Wkb = (ushort_t*)(ws + 19267584);
    ushort_t* Wvb = (ushort_t*)(ws + 20316160);
    ushort_t* Wob = (ushort_t*)(ws + 21364736);

    // prep: x cast + LoRA-A(q,k,v) + weight casts + rope table (transposed)
    prep_kernel<<<10752, 256, 0, stream>>>(
        x, xbf, qA, kA, vA, xa_q, xa_k, xa_v,
        Wq, Wk, Wv, Wo, Wqb, Wkb, Wvb, Wob, rope_tab);

    // QKV projection: LoRA fused; K roped, V bf16-transposed, Q plain
    gemm_qkv<<<dim3(M / 128, 32), 256, 0, stream>>>(
        xbf, Wqb, Wkb, Wvb, qb, kb, vtb,
        xa_q, xa_k, xa_v, qB, kB, vB, rope_tab);

    // flash attention (2-wave blocks, 32 q-rows/wave, ping-pong staging)
    attn_mfma6<<<512, 128, 0, stream>>>(qb, kb, vtb, attn_out, rope_tab);

    // output projection with fused o-LoRA
    lora_xa_bf16<<<M, 256, 0, stream>>>(attn_out, oA, xa_o, NQ * HD);
    gemm_wo<<<dim3(M / 128, HIDDEN / 128), 256, 0, stream>>>(
        attn_out, Wob, out, xa_o, oB);
}

// Round 9
// 448.903 us; speedup vs baseline: 1.0216x; 1.0104x over previous
//
#include <hip/hip_runtime.h>
#include <hip/hip_bf16.h>
#include <cmath>

// Problem constants
#define HIDDEN 2048
#define SEQ 2048
#define BATCH 2
#define NQ 16
#define NKV 8
#define HD 128
#define RANKL 8
#define LORA_SCALE 2.0f
#define INV_SQRT_D 0.08838834764831845f
#define LOG2E 1.4426950408889634f
#define SM_SCALE (INV_SQRT_D * LOG2E)

typedef unsigned short ushort_t;
typedef __bf16 bf16x8 __attribute__((ext_vector_type(8)));
typedef float f32x4 __attribute__((ext_vector_type(4)));

static __device__ __forceinline__ ushort_t f2bf(float f) {
    __hip_bfloat16 h = __float2bfloat16(f);
    return *(ushort_t*)&h;
}
static __device__ __forceinline__ float bf2f(ushort_t u) {
    unsigned int v = ((unsigned int)u) << 16;
    return __builtin_bit_cast(float, v);
}
static __device__ __forceinline__ void gload_lds16(const ushort_t* g, ushort_t* l) {
    __builtin_amdgcn_global_load_lds(
        (const __attribute__((address_space(1))) unsigned int*)g,
        (__attribute__((address_space(3))) unsigned int*)l, 16, 0, 0);
}

// ---------------------------------------------------------------------------
// Prep: x cast + q/k/v LoRA-A (blocks 0..4095), weight casts (4096..10239)
// ---------------------------------------------------------------------------
__global__ __launch_bounds__(256) void prep_kernel(
    const float* __restrict__ X, ushort_t* __restrict__ Xbf,
    const float* __restrict__ qA, const float* __restrict__ kA,
    const float* __restrict__ vA,
    float* __restrict__ oq, float* __restrict__ ok, float* __restrict__ ov,
    const float* __restrict__ Wq, const float* __restrict__ Wk,
    const float* __restrict__ Wv, const float* __restrict__ Wo,
    ushort_t* __restrict__ Wqb, ushort_t* __restrict__ Wkb,
    ushort_t* __restrict__ Wvb, ushort_t* __restrict__ Wob)
{
    __shared__ float wred[4][3][RANKL];
    const int blk = blockIdx.x;
    const int t = threadIdx.x;

    if (blk >= 4096) {                       // weight casts
        size_t i = (size_t)(blk - 4096) * 256 + t;
        const float* src; ushort_t* dst; size_t j;
        if (i < 524288)       { src = Wq; dst = Wqb; j = i; }
        else if (i < 786432)  { src = Wk; dst = Wkb; j = i - 524288; }
        else if (i < 1048576) { src = Wv; dst = Wvb; j = i - 786432; }
        else                  { src = Wo; dst = Wob; j = i - 1048576; }
        const float4* p = (const float4*)src + j * 2;
        float4 a = p[0], b = p[1];
        uint4 o;
        o.x = (unsigned int)f2bf(a.x) | ((unsigned int)f2bf(a.y) << 16);
        o.y = (unsigned int)f2bf(a.z) | ((unsigned int)f2bf(a.w) << 16);
        o.z = (unsigned int)f2bf(b.x) | ((unsigned int)f2bf(b.y) << 16);
        o.w = (unsigned int)f2bf(b.z) | ((unsigned int)f2bf(b.w) << 16);
        *(uint4*)(dst + j * 8) = o;
        return;
    }

    // x cast + LoRA-A for q,k,v
    int m = blk;
    int c0 = t * 8;
    const float* xr = X + (size_t)m * HIDDEN + c0;
    float4 a = *(const float4*)xr;
    float4 b = *(const float4*)(xr + 4);
    float xv[8] = {a.x, a.y, a.z, a.w, b.x, b.y, b.z, b.w};
    uint4 o;
    o.x = (unsigned int)f2bf(xv[0]) | ((unsigned int)f2bf(xv[1]) << 16);
    o.y = (unsigned int)f2bf(xv[2]) | ((unsigned int)f2bf(xv[3]) << 16);
    o.z = (unsigned int)f2bf(xv[4]) | ((unsigned int)f2bf(xv[5]) << 16);
    o.w = (unsigned int)f2bf(xv[6]) | ((unsigned int)f2bf(xv[7]) << 16);
    *(uint4*)(Xbf + (size_t)m * HIDDEN + c0) = o;

    float p[3][RANKL];
#pragma unroll
    for (int w = 0; w < 3; w++)
#pragma unroll
        for (int r = 0; r < RANKL; r++) p[w][r] = 0.f;
    const float* Aw[3] = {qA, kA, vA};
#pragma unroll
    for (int e = 0; e < 8; e++) {
        float x8 = xv[e];
#pragma unroll
        for (int w = 0; w < 3; w++)
#pragma unroll
            for (int r = 0; r < RANKL; r++)
                p[w][r] += x8 * Aw[w][r * HIDDEN + c0 + e];
    }
#pragma unroll
    for (int w = 0; w < 3; w++)
#pragma unroll
        for (int r = 0; r < RANKL; r++) {
            float v = p[w][r];
            v += __shfl_xor(v, 32); v += __shfl_xor(v, 16);
            v += __shfl_xor(v, 8);  v += __shfl_xor(v, 4);
            v += __shfl_xor(v, 2);  v += __shfl_xor(v, 1);
            p[w][r] = v;
        }
    int wave = t >> 6, lane = t & 63;
    if (lane == 0) {
#pragma unroll
        for (int w = 0; w < 3; w++)
#pragma unroll
            for (int r = 0; r < RANKL; r++) wred[wave][w][r] = p[w][r];
    }
    __syncthreads();
    if (t < 3 * RANKL) {
        int w = t / RANKL, r = t % RANKL;
        float s = wred[0][w][r] + wred[1][w][r] + wred[2][w][r] + wred[3][w][r];
        float* dst = (w == 0) ? oq : (w == 1) ? ok : ov;
        dst[(size_t)m * RANKL + r] = s;
    }
}

// bf16-input LoRA A-projection (for o)
__global__ __launch_bounds__(256) void lora_xa_bf16(
    const ushort_t* __restrict__ X, const float* __restrict__ Aw,
    float* __restrict__ out, int K)
{
    int m = blockIdx.x;
    int t = threadIdx.x;
    const ushort_t* xr = X + (size_t)m * K;
    float p[RANKL];
#pragma unroll
    for (int r = 0; r < RANKL; r++) p[r] = 0.f;
    for (int c = t; c < K; c += 256) {
        float xv = bf2f(xr[c]);
#pragma unroll
        for (int r = 0; r < RANKL; r++) p[r] += xv * Aw[r * K + c];
    }
#pragma unroll
    for (int r = 0; r < RANKL; r++) {
        float v = p[r];
        v += __shfl_xor(v, 32); v += __shfl_xor(v, 16);
        v += __shfl_xor(v, 8);  v += __shfl_xor(v, 4);
        v += __shfl_xor(v, 2);  v += __shfl_xor(v, 1);
        p[r] = v;
    }
    __shared__ float wred[4][RANKL];
    int wave = t >> 6, lane = t & 63;
    if (lane == 0) {
#pragma unroll
        for (int r = 0; r < RANKL; r++) wred[wave][r] = p[r];
    }
    __syncthreads();
    if (t < RANKL) {
        out[(size_t)m * RANKL + t] =
            wred[0][t] + wred[1][t] + wred[2][t] + wred[3][t];
    }
}

// ---------------------------------------------------------------------------
// bf16 MFMA GEMM core (m97 structure): C = A*B^T + lscale*xa*LB^T
// ---------------------------------------------------------------------------
static __device__ __forceinline__ void gemm_core(
    const ushort_t* __restrict__ A, const ushort_t* __restrict__ B,
    void* __restrict__ Cout, int N, int K, int bm, int bn,
    const float* __restrict__ xa, const float* __restrict__ LB,
    float lscale, int out_bf16, ushort_t* As, ushort_t* Bs)
{
    const int t = threadIdx.x;
    const int lane = t & 63;
    const int w = t >> 6;
    const int quad = lane >> 4;
    const int c = lane & 15;

    const int wm = (w & 1) * 64;
    const int wn = (w >> 1) * 64;

    f32x4 acc[4][4];
#pragma unroll
    for (int i = 0; i < 4; i++)
#pragma unroll
        for (int j = 0; j < 4; j++) acc[i][j] = (f32x4){0.f, 0.f, 0.f, 0.f};

    const int p0 = w * 64 + lane;
    const int p1 = 256 + w * 64 + lane;
    const int r0 = p0 >> 2, g0 = (p0 & 3) ^ ((p0 >> 3) & 3);
    const int r1 = p1 >> 2, g1 = (p1 & 3) ^ ((p1 >> 3) & 3);
    const ushort_t* gA0 = A + (size_t)(bm + r0) * K + g0 * 8;
    const ushort_t* gA1 = A + (size_t)(bm + r1) * K + g1 * 8;
    const ushort_t* gB0 = B + (size_t)(bn + r0) * K + g0 * 8;
    const ushort_t* gB1 = B + (size_t)(bn + r1) * K + g1 * 8;
    ushort_t* lA0 = As + (size_t)(w * 64) * 8;
    ushort_t* lA1 = As + (size_t)(256 + w * 64) * 8;
    ushort_t* lB0 = Bs + (size_t)(w * 64) * 8;
    ushort_t* lB1 = Bs + (size_t)(256 + w * 64) * 8;

    const int csw = quad ^ ((c >> 1) & 3);

    for (int k0 = 0; k0 < K; k0 += 32) {
        __syncthreads();
        gload_lds16(gA0 + k0, lA0);
        gload_lds16(gA1 + k0, lA1);
        gload_lds16(gB0 + k0, lB0);
        gload_lds16(gB1 + k0, lB1);
        __syncthreads();

        bf16x8 af[4], bfr[4];
#pragma unroll
        for (int mt = 0; mt < 4; mt++)
            af[mt] = *(const bf16x8*)&As[((wm + mt * 16 + c) * 4 + csw) * 8];
#pragma unroll
        for (int nt = 0; nt < 4; nt++)
            bfr[nt] = *(const bf16x8*)&Bs[((wn + nt * 16 + c) * 4 + csw) * 8];
#pragma unroll
        for (int mt = 0; mt < 4; mt++)
#pragma unroll
            for (int nt = 0; nt < 4; nt++)
                acc[mt][nt] = __builtin_amdgcn_mfma_f32_16x16x32_bf16(
                    af[mt], bfr[nt], acc[mt][nt], 0, 0, 0);
    }

    float lb[4][RANKL];
#pragma unroll
    for (int nt = 0; nt < 4; nt++) {
        int col = bn + wn + nt * 16 + c;
        float4 u = *(const float4*)&LB[(size_t)col * RANKL];
        float4 v = *(const float4*)&LB[(size_t)col * RANKL + 4];
        lb[nt][0] = u.x; lb[nt][1] = u.y; lb[nt][2] = u.z; lb[nt][3] = u.w;
        lb[nt][4] = v.x; lb[nt][5] = v.y; lb[nt][6] = v.z; lb[nt][7] = v.w;
    }
#pragma unroll
    for (int mt = 0; mt < 4; mt++) {
        float la[4][RANKL];
#pragma unroll
        for (int r = 0; r < 4; r++) {
            int row = bm + wm + mt * 16 + quad * 4 + r;
            float4 u = *(const float4*)&xa[(size_t)row * RANKL];
            float4 v = *(const float4*)&xa[(size_t)row * RANKL + 4];
            la[r][0] = u.x; la[r][1] = u.y; la[r][2] = u.z; la[r][3] = u.w;
            la[r][4] = v.x; la[r][5] = v.y; la[r][6] = v.z; la[r][7] = v.w;
        }
#pragma unroll
        for (int nt = 0; nt < 4; nt++) {
#pragma unroll
            for (int r = 0; r < 4; r++) {
                float s = 0.f;
#pragma unroll
                for (int k = 0; k < RANKL; k++) s += la[r][k] * lb[nt][k];
                float val = acc[mt][nt][r] + lscale * s;
                size_t row = bm + wm + mt * 16 + quad * 4 + r;
                size_t col = bn + wn + nt * 16 + c;
                if (out_bf16)
                    ((ushort_t*)Cout)[row * N + col] = f2bf(val);
                else
                    ((float*)Cout)[row * N + col] = val;
            }
        }
    }
}

// Fused QKV projection (light epilogue): grid (32, 32)
__global__ __launch_bounds__(256) void gemm_qkv(
    const ushort_t* __restrict__ A,
    const ushort_t* __restrict__ Wqb, const ushort_t* __restrict__ Wkb,
    const ushort_t* __restrict__ Wvb,
    ushort_t* __restrict__ q_lin, ushort_t* __restrict__ k_lin,
    ushort_t* __restrict__ v_lin,
    const float* __restrict__ xa_q, const float* __restrict__ xa_k,
    const float* __restrict__ xa_v,
    const float* __restrict__ qB, const float* __restrict__ kB,
    const float* __restrict__ vB)
{
    __shared__ ushort_t As[128 * 32];
    __shared__ ushort_t Bs[128 * 32];
    int bc = blockIdx.y;
    const ushort_t* B; ushort_t* Cout; const float* xa; const float* LB;
    int N, bn;
    if (bc < 16)      { B = Wqb; Cout = q_lin; xa = xa_q; LB = qB; N = 2048; bn = bc * 128; }
    else if (bc < 24) { B = Wkb; Cout = k_lin; xa = xa_k; LB = kB; N = 1024; bn = (bc - 16) * 128; }
    else              { B = Wvb; Cout = v_lin; xa = xa_v; LB = vB; N = 1024; bn = (bc - 24) * 128; }
    gemm_core(A, B, Cout, N, HIDDEN, blockIdx.x * 128, bn, xa, LB,
              LORA_SCALE, 1, As, Bs);
}

// Output projection (fp32 out)
__global__ __launch_bounds__(256) void gemm_wo(
    const ushort_t* __restrict__ A, const ushort_t* __restrict__ Wob,
    float* __restrict__ out, const float* __restrict__ xa_o,
    const float* __restrict__ oB)
{
    __shared__ ushort_t As[128 * 32];
    __shared__ ushort_t Bs[128 * 32];
    gemm_core(A, Wob, out, HIDDEN, NQ * HD, blockIdx.x * 128, blockIdx.y * 128,
              xa_o, oB, LORA_SCALE, 0, As, Bs);
}

// ---------------------------------------------------------------------------
// Fused rope(Q,K relayout) + V transpose.
// blocks 0..4095: rope one (b,s) row (24 heads x 64 pairs, 6 items/thread).
// blocks 4096..5119: V 64x64 transpose tiles -> vtb [b][kvh][d][s].
// ---------------------------------------------------------------------------
__global__ __launch_bounds__(256) void rope_vt(
    const ushort_t* __restrict__ qlin, const ushort_t* __restrict__ klin,
    const ushort_t* __restrict__ vlin,
    ushort_t* __restrict__ qb, ushort_t* __restrict__ kb,
    ushort_t* __restrict__ vtb)
{
    __shared__ ushort_t tile[64 * 72];
    const int t = threadIdx.x;

    if (blockIdx.x < 4096) {
        int bs = blockIdx.x;
        int s = bs & (SEQ - 1);
        int b = bs >> 11;
        int p = t & 63;
        float inv = exp2f(-(float)p * 0.20762050593046f); // 10000^(-p/64)
        float ang = (float)s * inv;
        float cc = cosf(ang), si = sinf(ang);
#pragma unroll
        for (int j = 0; j < 6; j++) {
            int item = t + 256 * j;
            int hh = item >> 6;       // 0..23
            unsigned int pk;
            ushort_t* dst;
            if (hh < NQ) {
                pk = *(const unsigned int*)&qlin[(size_t)bs * (NQ * HD) + hh * HD + 2 * p];
                dst = qb + (((size_t)(b * NQ + hh) * SEQ) + s) * HD + 2 * p;
            } else {
                int kh = hh - NQ;
                pk = *(const unsigned int*)&klin[(size_t)bs * (NKV * HD) + kh * HD + 2 * p];
                dst = kb + (((size_t)(b * NKV + kh) * SEQ) + s) * HD + 2 * p;
            }
            float xr = bf2f((ushort_t)(pk & 0xffff));
            float xi = bf2f((ushort_t)(pk >> 16));
            float rr = xr * cc - xi * si;
            float ri = xr * si + xi * cc;
            *(unsigned int*)dst = ((unsigned int)f2bf(ri) << 16) | f2bf(rr);
        }
        return;
    }

    // V transpose
    int id = blockIdx.x - 4096;          // 0..1023
    int bk = id & 15;
    int b = bk >> 3, kvh = bk & 7;
    int s0 = ((id >> 4) & 31) * 64;
    int d0 = (id >> 9) * 64;
#pragma unroll
    for (int i = 0; i < 2; i++) {
        int e = t + 256 * i;
        int r = e >> 3, cc = e & 7;
        uint4 v = *(const uint4*)&vlin[(size_t)(b * SEQ + s0 + r) * (NKV * HD)
                                       + kvh * HD + d0 + cc * 8];
        *(uint4*)&tile[r * 72 + cc * 8] = v;
    }
    __syncthreads();
#pragma unroll
    for (int i = 0; i < 2; i++) {
        int e = t + 256 * i;
        int dr = e >> 3, sc = e & 7;
        ushort_t tmp[8];
#pragma unroll
        for (int j = 0; j < 8; j++) tmp[j] = tile[(sc * 8 + j) * 72 + dr];
        *(uint4*)&vtb[((size_t)(b * NKV + kvh) * HD + d0 + dr) * SEQ + s0 + sc * 8]
            = *(uint4*)tmp;
    }
}

// ---------------------------------------------------------------------------
// MFMA flash attention v7.
// Block = 256 thr = 4 waves; 128-row q-block; wave owns 32 q-rows (2 m-tiles)
// -> each kf/vf ds_read_b128 feeds 2 MFMAs (halves LDS traffic per MFMA) and
// total K/V staging halves vs 64-row blocks. LPT scheduling: qb descending
// with blockIdx so heavy blocks dispatch first and light ones backfill.
// Single-buffer staging (v4 style), per-wave P at stride 68, constant-max
// softmax. Q,K bf16 [b][h/kvh][s][128] (pre-roped); V bf16 [b][kvh][d][s];
// O bf16 [b*s][h*128+d].
// ---------------------------------------------------------------------------
__global__ __launch_bounds__(256) void attn_mfma7(
    const ushort_t* __restrict__ Q, const ushort_t* __restrict__ K,
    const ushort_t* __restrict__ V, ushort_t* __restrict__ O)
{
    __shared__ ushort_t Ks[64 * 128];       // 16 KB
    __shared__ ushort_t Vs[128 * 64];       // 16 KB
    __shared__ ushort_t Psh[4][2][16 * 68]; // 17 KB [wave][mt]

    const int t = threadIdx.x;
    const int lane = t & 63;
    const int w = t >> 6;
    const int quad = lane >> 4;
    const int c = lane & 15;
    const int q4 = quad * 4;
    const int c7 = c & 7;

    const int qb = 15 - (blockIdx.x >> 5);  // heavy q-blocks first (LPT)
    const int head = blockIdx.x & 31;       // b*NQ + h
    const int h = head & (NQ - 1);
    const int b = head >> 4;
    const int kvh = b * NKV + (h >> 1);

    const ushort_t* Kg = K + (size_t)kvh * SEQ * HD;
    const ushort_t* Vg = V + (size_t)kvh * HD * SEQ;

    const ushort_t* gK[4]; const ushort_t* gV[4];
    int lo4[4];
#pragma unroll
    for (int i = 0; i < 4; i++) {
        int cid = t + 256 * i;
        int kr = cid >> 4, kc = cid & 15;
        gK[i] = Kg + (size_t)kr * HD + ((kc ^ (kr & 7)) * 8);
        int vd = cid >> 3, vc = cid & 7;
        gV[i] = Vg + (size_t)vd * SEQ + ((vc ^ (vd & 7)) * 8);
        lo4[i] = (i * 256 + (t & ~63)) * 8;
    }

    // Q fragments: rows qb*128 + w*32 + mt*16 + c (pre-roped)
    bf16x8 qf[2][4];
#pragma unroll
    for (int mt = 0; mt < 2; mt++) {
        const ushort_t* Qg = Q +
            ((size_t)head * SEQ + qb * 128 + w * 32 + mt * 16 + c) * HD;
#pragma unroll
        for (int ch = 0; ch < 4; ch++)
            qf[mt][ch] = *(const bf16x8*)(Qg + ch * 32 + quad * 8);
    }

    f32x4 o[2][8];
#pragma unroll
    for (int mt = 0; mt < 2; mt++)
#pragma unroll
        for (int i = 0; i < 8; i++) o[mt][i] = (f32x4){0.f, 0.f, 0.f, 0.f};
    float lp[2][4] = {{0.f, 0.f, 0.f, 0.f}, {0.f, 0.f, 0.f, 0.f}};

    const int ntiles = 2 * qb + 2;
    const int mask_from = 2 * qb;

    for (int tile = 0; tile < ntiles; ++tile) {
        const int j0 = tile * 64;
        __syncthreads();
#pragma unroll
        for (int i = 0; i < 4; i++)
            gload_lds16(gK[i] + (size_t)j0 * HD, &Ks[lo4[i]]);
#pragma unroll
        for (int i = 0; i < 4; i++)
            gload_lds16(gV[i] + j0, &Vs[lo4[i]]);
        __syncthreads();

        // ---- QK^T: each kf feeds both m-tiles
        f32x4 s[2][4];
#pragma unroll
        for (int tt = 0; tt < 4; tt++) {
            s[0][tt] = (f32x4){0.f, 0.f, 0.f, 0.f};
            s[1][tt] = (f32x4){0.f, 0.f, 0.f, 0.f};
        }
#pragma unroll
        for (int tt = 0; tt < 4; tt++) {
            const int krow = tt * 16 + c;
#pragma unroll
            for (int ch = 0; ch < 4; ch++) {
                bf16x8 kf = *(const bf16x8*)
                    &Ks[krow * 128 + (((ch * 4 + quad) ^ c7) * 8)];
                s[0][tt] = __builtin_amdgcn_mfma_f32_16x16x32_bf16(
                    qf[0][ch], kf, s[0][tt], 0, 0, 0);
                s[1][tt] = __builtin_amdgcn_mfma_f32_16x16x32_bf16(
                    qf[1][ch], kf, s[1][tt], 0, 0, 0);
            }
        }

        // ---- constant-max softmax, P to per-wave LDS
        const bool need_mask = (tile >= mask_from);
#pragma unroll
        for (int mt = 0; mt < 2; mt++) {
            ushort_t* Pw = Psh[w][mt];
            const int rowbase = qb * 128 + w * 32 + mt * 16;
#pragma unroll
            for (int r = 0; r < 4; r++) {
                const int row_g = rowbase + q4 + r;
#pragma unroll
                for (int tt = 0; tt < 4; tt++) {
                    float p = exp2f(s[mt][tt][r] * SM_SCALE);
                    if (need_mask && (j0 + tt * 16 + c > row_g)) p = 0.f;
                    Pw[(q4 + r) * 68 + tt * 16 + c] = f2bf(p);
                    lp[mt][r] += p;
                }
            }
        }

        // ---- P fragments (A-layout)
        bf16x8 pf[2][2];
#pragma unroll
        for (int mt = 0; mt < 2; mt++)
#pragma unroll
            for (int ch = 0; ch < 2; ch++) {
                int base = c * 68 + ch * 32 + quad * 8;
                uint2 aa = *(const uint2*)&Psh[w][mt][base];
                uint2 bb = *(const uint2*)&Psh[w][mt][base + 4];
                uint4 u; u.x = aa.x; u.y = aa.y; u.z = bb.x; u.w = bb.y;
                pf[mt][ch] = __builtin_bit_cast(bf16x8, u);
            }

        // ---- PV: each vf feeds both m-tiles
#pragma unroll
        for (int dt = 0; dt < 8; dt++) {
            const int vrow = dt * 16 + c;
#pragma unroll
            for (int ch = 0; ch < 2; ch++) {
                bf16x8 vf = *(const bf16x8*)
                    &Vs[vrow * 64 + (((ch * 4 + quad) ^ c7) * 8)];
                o[0][dt] = __builtin_amdgcn_mfma_f32_16x16x32_bf16(
                    pf[0][ch], vf, o[0][dt], 0, 0, 0);
                o[1][dt] = __builtin_amdgcn_mfma_f32_16x16x32_bf16(
                    pf[1][ch], vf, o[1][dt], 0, 0, 0);
            }
        }
    }

    // ---- epilogue
#pragma unroll
    for (int mt = 0; mt < 2; mt++) {
        float inv[4];
#pragma unroll
        for (int r = 0; r < 4; r++) {
            float v = lp[mt][r];
            v += __shfl_xor(v, 1);
            v += __shfl_xor(v, 2);
            v += __shfl_xor(v, 4);
            v += __shfl_xor(v, 8);
            inv[r] = 1.f / v;
        }
        size_t base = ((size_t)b * SEQ + qb * 128 + w * 32 + mt * 16 + q4)
                      * (NQ * HD) + h * HD + c;
#pragma unroll
        for (int r = 0; r < 4; r++)
#pragma unroll
            for (int dt = 0; dt < 8; dt++)
                O[base + (size_t)r * (NQ * HD) + dt * 16] =
                    f2bf(o[mt][dt][r] * inv[r]);
    }
}

// ---------------------------------------------------------------------------
// Launch
// ---------------------------------------------------------------------------
extern "C" void kernel_launch(void* const* d_in, const int* in_sizes, int n_in,
                              void* d_out, int out_size, void* d_ws, size_t ws_size,
                              hipStream_t stream)
{
    const float* x  = (const float*)d_in[0];
    const float* Wq = (const float*)d_in[1];
    const float* Wk = (const float*)d_in[2];
    const float* Wv = (const float*)d_in[3];
    const float* Wo = (const float*)d_in[4];
    const float* qA = (const float*)d_in[5];
    const float* qB = (const float*)d_in[6];
    const float* kA = (const float*)d_in[7];
    const float* kB = (const float*)d_in[8];
    const float* vA = (const float*)d_in[9];
    const float* vB = (const float*)d_in[10];
    const float* oA = (const float*)d_in[11];
    const float* oB = (const float*)d_in[12];
    float* out = (float*)d_out;
    float* ws = (float*)d_ws;

    const int M = BATCH * SEQ;           // 4096

    float* xa_q = ws;
    float* xa_k = ws + 32768;
    float* xa_v = ws + 65536;
    float* xa_o = ws + 98304;
    ushort_t* q_lin = (ushort_t*)(ws + 131072);     // bf16 4096x2048
    ushort_t* k_lin = (ushort_t*)(ws + 4325376);    // bf16 4096x1024
    ushort_t* v_lin = (ushort_t*)(ws + 6422528);    // bf16 4096x1024
    ushort_t* qb    = (ushort_t*)(ws + 8519680);    // bf16 [B][16][S][128]
    ushort_t* kb    = (ushort_t*)(ws + 12713984);   // bf16 [B][8][S][128]
    ushort_t* vtb   = (ushort_t*)(ws + 14811136);   // bf16 [B][8][128][S]
    ushort_t* attn_out = (ushort_t*)(ws + 16908288);// bf16 [4096][2048]
    ushort_t* xbf   = (ushort_t*)(ws + 21102592);   // bf16 4096x2048
    ushort_t* Wqb   = (ushort_t*)(ws + 25296896);
    ushort_t* Wkb   = (ushort_t*)(ws + 27394048);
    ushort_t* Wvb   = (ushort_t*)(ws + 28442624);
    ushort_t* Wob   = (ushort_t*)(ws + 29491200);

    // prep: x cast + LoRA-A(q,k,v) + weight casts
    prep_kernel<<<10240, 256, 0, stream>>>(
        x, xbf, qA, kA, vA, xa_q, xa_k, xa_v,
        Wq, Wk, Wv, Wo, Wqb, Wkb, Wvb, Wob);

    // fused QKV projection (light epilogue) with fused LoRA
    gemm_qkv<<<dim3(M / 128, 32), 256, 0, stream>>>(
        xbf, Wqb, Wkb, Wvb, q_lin, k_lin, v_lin,
        xa_q, xa_k, xa_v, qB, kB, vB);

    // rope q,k + transpose v (one kernel)
    rope_vt<<<5120, 256, 0, stream>>>(q_lin, k_lin, v_lin, qb, kb, vtb);

    // flash attention (128-row q-blocks, 32 q-rows/wave, LPT order)
    attn_mfma7<<<512, 256, 0, stream>>>(qb, kb, vtb, attn_out);

    // output projection with fused o-LoRA
    lora_xa_bf16<<<M, 256, 0, stream>>>(attn_out, oA, xa_o, NQ * HD);
    gemm_wo<<<dim3(M / 128, HIDDEN / 128), 256, 0, stream>>>(
        attn_out, Wob, out, xa_o, oB);
}